// Round 13
// baseline (649.448 us; speedup 1.0000x reference)
//
#include <hip/hip_runtime.h>
#include <cstdint>
#include <cstddef>

// Problem shape (fixed by the reference): B=8, C=192, Tx=512, Ty=2048.
#define BB 8
#define CC 192
#define TXX 512
#define TYY 2048

#define NEG_INF (-1e9f)
#define HALF_LOG_2PI 0.9189385332046727f  // 0.5*log(2*pi)

// ---- output layout (floats, concatenated in return order) ----
#define O1 8388608
#define O2 11534336
#define O3 14680064
#define O4 14680065

// ---- workspace layout (bytes) ----
#define WS_NEG   0           // neg_cent fp32 [B,Ty,Tx]           33,554,432 B
#define WS_S     33554432    // s_p_sq_r [B,C,Tx]                  3,145,728 B
#define WS_MSR   36700160    // m_p * s  [B,C,Tx]                  3,145,728 B
#define WS_BIAS  39845888    // nc1+nc4  [B,Tx]                       16,384 B
#define WS_DIRS  39862272    // dir bits [B,Ty/4,64] dwords        1,048,576 B
#define WS_IDX   40910848    // idx_map  [B,Ty] int                   65,536 B
#define WS_LENS  40976384    // int text_len[8], spec_len[8]             64 B
#define WS_PART  40976448    // kl partials [3072] float; ALSO the
                             // producer-consumer cnt[256] ints during k_mega
                             // (lifetimes disjoint: cnt dies before k_gather
                             // writes partials)

typedef float f32x4 __attribute__((ext_vector_type(4)));

// ---------------------------------------------------------------------------
// k_pre (R26): fused zero + prep + bias + len (+ R27: zero the cnt flags).
// ---------------------------------------------------------------------------
#define PRE_NZERO 2048
#define PRE_NPREP 3072
#define PRE_NBIAS 16
#define PRE_NLEN  8
__global__ __launch_bounds__(256) void k_pre(const float* __restrict__ logs_p,
                                             const float* __restrict__ m_p,
                                             const float* __restrict__ tmask,
                                             const float* __restrict__ smask,
                                             float* __restrict__ s,
                                             float* __restrict__ msr,
                                             float* __restrict__ bias,
                                             int* __restrict__ lens,
                                             float* __restrict__ out,
                                             int* __restrict__ cnt) {
    int blk = blockIdx.x, tid = threadIdx.x;
    if (blk < PRE_NZERO) {
        int64_t i = (int64_t)blk * 256 + tid;
        const int64_t n4 = (int64_t)BB * TYY * TXX / 4;
        float4 z4 = make_float4(0.f, 0.f, 0.f, 0.f);
        float4* p4 = (float4*)out;
        for (int64_t k = i; k < n4; k += (int64_t)PRE_NZERO * 256) p4[k] = z4;
        if (i < BB * TXX) out[O4 + i] = 0.0f;
    } else if (blk < PRE_NZERO + PRE_NPREP) {
        int i = (blk - PRE_NZERO) * 256 + tid;
        float lp = logs_p[i], m = m_p[i];
        float sv = expf(-2.0f * lp);
        s[i] = sv;
        msr[i] = m * sv;
    } else if (blk < PRE_NZERO + PRE_NPREP + PRE_NBIAS) {
        int i = (blk - PRE_NZERO - PRE_NPREP) * 256 + tid;  // B*Tx = 4096
        int b = i >> 9, x = i & (TXX - 1);
        size_t base = (size_t)b * CC * TXX + x;
        const float* lpb = logs_p + base;
        const float* mb  = m_p + base;
        float acc = 0.f;
#pragma unroll 8
        for (int c = 0; c < CC; ++c) {
            float lp = lpb[(size_t)c * TXX];
            float m  = mb[(size_t)c * TXX];
            float msv = m * expf(-2.0f * lp);   // == msr[c] bitwise
            acc += -HALF_LOG_2PI - lp - 0.5f * m * msv;
        }
        bias[i] = acc;
    } else if (blk < PRE_NZERO + PRE_NPREP + PRE_NBIAS + PRE_NLEN) {
        __shared__ float red[256];
        int b = blk - (PRE_NZERO + PRE_NPREP + PRE_NBIAS);
        float ts = 0.f;
        for (int i = tid; i < TXX; i += 256) ts += tmask[b * TXX + i];
        red[tid] = ts; __syncthreads();
        for (int s2 = 128; s2 > 0; s2 >>= 1) { if (tid < s2) red[tid] += red[tid + s2]; __syncthreads(); }
        if (tid == 0) lens[b] = (int)(red[0] + 0.5f);
        __syncthreads();
        float ss = 0.f;
        for (int i = tid; i < TYY; i += 256) ss += smask[b * TYY + i];
        red[tid] = ss; __syncthreads();
        for (int s2 = 128; s2 > 0; s2 >>= 1) { if (tid < s2) red[tid] += red[tid + s2]; __syncthreads(); }
        if (tid == 0) lens[8 + b] = (int)(red[0] + 0.5f);
    } else {
        cnt[tid] = 0;   // 256 producer-consumer flags (8 b x 32 chunks)
    }
}

// ---------------------------------------------------------------------------
// k_mega (R27): producer-consumer fusion of gemm + fwd + bwd.
//
// R26 ledger: total-fwd = 338us of non-fwd time; gemm (never in top-5,
// absolute cost unknown 70-250us) is paid SERIALLY before fwd although fwd
// uses 8/256 CUs and consumes neg rows in ascending t. Single stream forbids
// cross-kernel overlap -> fuse into ONE kernel:
//   blocks 0..7   : v5 fwd (64 lanes) + R26 pipelined bwd, gated per
//                   64-row chunk on agent-scope acquire flags.
//   blocks 8..2055: proven 64x64 gemm, t-chunk-major order (all 64 tiles of
//                   rows 0..63 first) so production outruns consumption
//                   (5.8us/chunk consumption; production >=2x even if the
//                   regalloc coupling drops gemm occupancy).
// Sync protocol: producer writes tile -> __threadfence (release, drains
// stores + wbL2) -> __syncthreads -> tid0 release-atomicAdd cnt[b][tch].
// MASKED tiles increment too => every cnt provably reaches 8 => consumers
// cannot spin forever; producers never wait => no deadlock possible.
// Consumer: acquire-load spin (s_sleep-throttled) once per chunk BEFORE
// issuing that chunk's prefetch LOADGs (the acquire's vmcnt drain is ~32
// small bubbles, ~2-5% of fwd). Replay-safe: cnt re-zeroed by k_pre each
// graph iteration; rocprof solo-replay sees cnt>=8 -> no spin.
// ---------------------------------------------------------------------------
#define GLOAD4(DST, PTR, OFF)                                             \
    asm volatile("global_load_dwordx4 %0, %1, off offset:" #OFF           \
                 : "=v"(DST) : "v"(PTR) : "memory")

#define WAIT_VM(N) do {                                                   \
    asm volatile("s_waitcnt vmcnt(" #N ")" ::: "memory");                 \
    __builtin_amdgcn_sched_barrier(0);                                    \
} while (0)

#define LOADG(DST, G) do {                                                \
    const char* p0_ = (const char*)nc4 + (size_t)(G) * 16384 + lane * 32; \
    const char* p2_ = p0_ + 4096;                                         \
    const char* p4_ = p0_ + 8192;                                         \
    const char* p6_ = p0_ + 12288;                                        \
    GLOAD4(DST[0],  p0_, 0);    GLOAD4(DST[1],  p0_, 16);                 \
    GLOAD4(DST[2],  p0_, 2048); GLOAD4(DST[3],  p0_, 2064);               \
    GLOAD4(DST[4],  p2_, 0);    GLOAD4(DST[5],  p2_, 16);                 \
    GLOAD4(DST[6],  p2_, 2048); GLOAD4(DST[7],  p2_, 2064);               \
    GLOAD4(DST[8],  p4_, 0);    GLOAD4(DST[9],  p4_, 16);                 \
    GLOAD4(DST[10], p4_, 2048); GLOAD4(DST[11], p4_, 2064);               \
    GLOAD4(DST[12], p6_, 0);    GLOAD4(DST[13], p6_, 16);                 \
    GLOAD4(DST[14], p6_, 2048); GLOAD4(DST[15], p6_, 2064);               \
} while (0)

#define DPROW(CUR, YB, R) do {                                                \
    int y_ = (YB) + (R);                                                      \
    float s0_ = CUR[2*(R)][0],   s1_ = CUR[2*(R)][1];                         \
    float s2_ = CUR[2*(R)][2],   s3_ = CUR[2*(R)][3];                         \
    float s4_ = CUR[2*(R)+1][0], s5_ = CUR[2*(R)+1][1];                       \
    float s6_ = CUR[2*(R)+1][2], s7_ = CUR[2*(R)+1][3];                       \
    unsigned d_ = 0;                                                          \
    if (y_ == 0) {                                                            \
        if (lane == 0) v[0] = s0_;   /* only x==0 scored on row 0 */          \
    } else {                                                                  \
        float pl_ = __int_as_float(__builtin_amdgcn_update_dpp(               \
            0, __float_as_int(v[7]), 0x138, 0xF, 0xF, false));                \
        if (lane == 0) pl_ = NEG_INF;                                         \
        float n0_ = s0_ + fmaxf(v[0], pl_);  if (pl_  > v[0]) d_ |= 1u;       \
        float n1_ = s1_ + fmaxf(v[1], v[0]); if (v[0] > v[1]) d_ |= 2u;       \
        float n2_ = s2_ + fmaxf(v[2], v[1]); if (v[1] > v[2]) d_ |= 4u;       \
        float n3_ = s3_ + fmaxf(v[3], v[2]); if (v[2] > v[3]) d_ |= 8u;       \
        float n4_ = s4_ + fmaxf(v[4], v[3]); if (v[3] > v[4]) d_ |= 16u;      \
        float n5_ = s5_ + fmaxf(v[5], v[4]); if (v[4] > v[5]) d_ |= 32u;      \
        float n6_ = s6_ + fmaxf(v[6], v[5]); if (v[5] > v[6]) d_ |= 64u;      \
        float n7_ = s7_ + fmaxf(v[7], v[6]); if (v[6] > v[7]) d_ |= 128u;     \
        v[0] = n0_; v[1] = n1_; v[2] = n2_; v[3] = n3_;                       \
        v[4] = n4_; v[5] = n5_; v[6] = n6_; v[7] = n7_;                       \
    }                                                                         \
    unsigned t_ = (unsigned)(y_ - 8 * lane);                                  \
    if (t_ < 8u) d_ |= 1u << t_;          /* fold x==y for backtrack */       \
    acc |= d_ << (((R) & 3) * 8);                                             \
    if (((R) & 3) == 3) { db32[(y_ >> 2) * 64 + lane] = acc; acc = 0; }       \
} while (0)

#define SPIN_CHUNK(C) do {                                                    \
    while (__hip_atomic_load(&cnt[(b << 5) + (C)], __ATOMIC_ACQUIRE,          \
                             __HIP_MEMORY_SCOPE_AGENT) < 8)                   \
        __builtin_amdgcn_s_sleep(2);                                          \
} while (0)

#define FWD_ITER(G, CUR, NXT) do {                                \
    int g_ = (G);                                                 \
    if (g_ + 2 < ng) {                                            \
        if (((g_ + 2) & 7) == 0) SPIN_CHUNK((g_ + 2) >> 3);       \
        LOADG(NXT, g_ + 2);  /* prefetch 2 ahead */               \
        WAIT_VM(32);                                              \
    } else if (g_ + 1 < ng) {                                     \
        WAIT_VM(16);                                              \
    } else {                                                      \
        WAIT_VM(0);                                               \
    }                                                             \
    int yb_ = 8 * g_;                                             \
    DPROW(CUR, yb_, 0); DPROW(CUR, yb_, 1);                       \
    DPROW(CUR, yb_, 2); DPROW(CUR, yb_, 3);                       \
    DPROW(CUR, yb_, 4); DPROW(CUR, yb_, 5);                       \
    DPROW(CUR, yb_, 6); DPROW(CUR, yb_, 7);                       \
} while (0)

#define LOADW(D0, D1, D2, WB, QROW, BOFF) do {                            \
    const uint32_t* p_ = db32 + (QROW) + 4 * (WB);                        \
    uint32_t a0_=p_[0], a1_=p_[1], a2_=p_[2],  a3_=p_[3];                 \
    uint32_t b0_=p_[4], b1_=p_[5], b2_=p_[6],  b3_=p_[7];                 \
    uint32_t c0_=p_[8], c1_=p_[9], c2_=p_[10], c3_=p_[11];                \
    D0 = ((a0_>>(BOFF))&0xffu)        | (((a1_>>(BOFF))&0xffu)<<8) |      \
         (((a2_>>(BOFF))&0xffu)<<16)  | (((a3_>>(BOFF))&0xffu)<<24);      \
    D1 = ((b0_>>(BOFF))&0xffu)        | (((b1_>>(BOFF))&0xffu)<<8) |      \
         (((b2_>>(BOFF))&0xffu)<<16)  | (((b3_>>(BOFF))&0xffu)<<24);      \
    D2 = ((c0_>>(BOFF))&0xffu)        | (((c1_>>(BOFF))&0xffu)<<8) |      \
         (((c2_>>(BOFF))&0xffu)<<16)  | (((c3_>>(BOFF))&0xffu)<<24);      \
} while (0)

__global__ __launch_bounds__(256) void k_mega(const float* __restrict__ z,
                                              const float* __restrict__ msr,
                                              const float* __restrict__ sarr,
                                              const float* __restrict__ bias,
                                              const int* __restrict__ lens,
                                              float* __restrict__ neg,
                                              uint32_t* __restrict__ dirs,
                                              int* __restrict__ idx_map,
                                              float* __restrict__ out,
                                              int* __restrict__ cnt) {
    __shared__ float Zs[16][68], Ms[16][68], Ss[16][68];  // gemm staging
    int id = blockIdx.x;

    if (id < 8) {
        // ================= consumer: fwd (v5) + bwd (R26) =================
        if (threadIdx.x >= 64) return;
        int b = id, lane = threadIdx.x;
        const float* nc4 = neg + (size_t)b * TYY * TXX;
        uint32_t* db32 = dirs + (size_t)b * (TYY / 4) * 64;
        int slen = lens[8 + b];
        int ng = (slen + 7) >> 3;    // 192..256

        float v[8];
#pragma unroll
        for (int j = 0; j < 8; ++j) v[j] = NEG_INF;
        unsigned acc = 0;

        f32x4 bufA[16], bufB[16], bufC[16];
        SPIN_CHUNK(0);               // rows 0..63 produced
        LOADG(bufA, 0);
        LOADG(bufB, 1);

        for (int p = 0; p < ng; p += 3) {
            FWD_ITER(p, bufA, bufC);
            if (p + 1 < ng) FWD_ITER(p + 1, bufB, bufA);
            if (p + 2 < ng) FWD_ITER(p + 2, bufC, bufB);
        }

        // ---- fused backtrack (dirs stores drained first) ----
        WAIT_VM(0);
        {
            int tlen = lens[b];
            int idx = tlen - 1;
            int y0 = slen - 1;
            int wb;
            uint32_t W0 = 0, W1 = 0, W2 = 0;
            {
                int yy = y0 - lane; if (yy < 0) yy = 0;
                int qrow = (yy >> 2) * 64, boff = (yy & 3) * 8;
                int t = (idx >> 5) - 1; if (t < 0) t = 0; if (t > 13) t = 13;
                wb = t;
                if (lane < 32) LOADW(W0, W1, W2, wb, qrow, boff);
            }
            while (y0 >= 0) {
                int w0 = (idx >> 5) - 1; if (w0 < 0) w0 = 0; if (w0 > 14) w0 = 14;
                int s = w0 - wb; if (s < 0) s = 0; if (s > 1) s = 1;
                uint32_t lo = s ? W1 : W0;
                uint32_t hi = s ? W2 : W1;
                int base = (wb + s) << 5;
                uint32_t N0 = 0, N1 = 0, N2 = 0;
                int idxm = idx - 32; if (idxm < 0) idxm = 0;
                int wbn = (idxm >> 5) - 1; if (wbn < 0) wbn = 0; if (wbn > 13) wbn = 13;
                {
                    int yn = y0 - 32 - lane; if (yn < 0) yn = 0;
                    int qn = (yn >> 2) * 64, bn = (yn & 3) * 8;
                    if (lane < 32) LOADW(N0, N1, N2, wbn, qn, bn);
                }
                int nsteps = (y0 + 1 < 32) ? y0 + 1 : 32;
                int cap = 0;
#pragma unroll
                for (int j = 0; j < 32; ++j) {
                    if (lane == j) cap = idx;
                    uint32_t l = (uint32_t)__builtin_amdgcn_readlane((int)lo, j);
                    uint32_t h = (uint32_t)__builtin_amdgcn_readlane((int)hi, j);
                    int bp = idx - base;
                    uint32_t word = (bp & 32) ? h : l;
                    idx -= (int)((word >> (bp & 31)) & 1u);
                }
                if (lane < nsteps) {
                    int y = y0 - lane;
                    idx_map[b * TYY + y] = cap;
                    out[((size_t)(b * TYY + y)) * TXX + cap] = 1.0f;
                    atomicAdd(&out[O4 + b * TXX + cap], 1.0f);
                }
                wb = wbn; W0 = N0; W1 = N1; W2 = N2;
                y0 -= 32;
            }
        }
        return;
    }

    // ================= producer: 64x64 gemm, t-chunk-major =================
    int gid = id - 8;
    int tch = gid >> 6;              // 0..31, ascending first
    int rem = gid & 63;
    int b   = rem >> 3;
    int x0  = (rem & 7) * 64;
    int t0  = tch * 64;
    int tid = threadIdx.x;
    bool live = (x0 < lens[b] && t0 < lens[8 + b]);   // block-uniform
    if (live) {
        int tx = tid & 15, ty = tid >> 4;
        const float* zb = z    + (size_t)b * CC * TYY;
        const float* mb = msr  + (size_t)b * CC * TXX;
        const float* sb = sarr + (size_t)b * CC * TXX;
        int lr = tid >> 4, lc = (tid & 15) * 4;
        float gacc[4][4] = {};
        for (int k0 = 0; k0 < CC; k0 += 16) {
            float4 zv = *(const float4*)(zb + (size_t)(k0 + lr) * TYY + t0 + lc);
            float4 mv = *(const float4*)(mb + (size_t)(k0 + lr) * TXX + x0 + lc);
            float4 sv = *(const float4*)(sb + (size_t)(k0 + lr) * TXX + x0 + lc);
            __syncthreads();
            *(float4*)&Zs[lr][lc] = zv;
            *(float4*)&Ms[lr][lc] = mv;
            *(float4*)&Ss[lr][lc] = sv;
            __syncthreads();
#pragma unroll
            for (int k = 0; k < 16; ++k) {
                float4 a4  = *(const float4*)&Zs[k][ty * 4];
                float4 bm4 = *(const float4*)&Ms[k][tx * 4];
                float4 bs4 = *(const float4*)&Ss[k][tx * 4];
                float av[4]  = {a4.x, a4.y, a4.z, a4.w};
                float bmv[4] = {bm4.x, bm4.y, bm4.z, bm4.w};
                float bsv[4] = {bs4.x, bs4.y, bs4.z, bs4.w};
#pragma unroll
                for (int i2 = 0; i2 < 4; ++i2) {
                    float a2 = -0.5f * av[i2] * av[i2];
#pragma unroll
                    for (int j = 0; j < 4; ++j)
                        gacc[i2][j] += av[i2] * bmv[j] + a2 * bsv[j];
                }
            }
        }
        float4 b4 = *(const float4*)(bias + b * TXX + x0 + tx * 4);
        float bv[4] = {b4.x, b4.y, b4.z, b4.w};
#pragma unroll
        for (int i2 = 0; i2 < 4; ++i2) {
            int t = t0 + ty * 4 + i2;
            float4 o;
            o.x = gacc[i2][0] + bv[0]; o.y = gacc[i2][1] + bv[1];
            o.z = gacc[i2][2] + bv[2]; o.w = gacc[i2][3] + bv[3];
            *(float4*)(neg + ((size_t)b * TYY + t) * TXX + x0 + tx * 4) = o;
        }
    }
    __threadfence();                 // release: neg writes agent-visible
    __syncthreads();                 // all threads' fences done
    if (tid == 0)
        __hip_atomic_fetch_add(&cnt[(b << 5) + tch], 1,
                               __ATOMIC_RELEASE, __HIP_MEMORY_SCOPE_AGENT);
}

// Gather m_p/logs_p onto spec frames via idx_map; fused KL partial sums.
__global__ __launch_bounds__(256) void k_gather(const float* __restrict__ z_p,
                                                const float* __restrict__ m_p,
                                                const float* __restrict__ logs_p,
                                                const float* __restrict__ logs_q,
                                                const int* __restrict__ lens,
                                                const int* __restrict__ idx_map,
                                                float* __restrict__ out,
                                                float* __restrict__ partials) {
    const int S = BB * CC * TYY / 4;
    int base = blockIdx.x * 256 + threadIdx.x;
    float klsum = 0.f;
#pragma unroll
    for (int r = 0; r < 4; ++r) {
        int i = base + r * S;
        int t = i & (TYY - 1);
        int bc = i >> 11;
        int b = bc / CC;
        float ma = 0.f, la = 0.f;
        if (t < lens[8 + b]) {
            int x = idx_map[b * TYY + t];
            size_t off = (size_t)bc * TXX + x;
            ma = m_p[off];
            la = logs_p[off];
            float zv = z_p[i], lq = logs_q[i];
            float dz = zv - ma;
            klsum += la - lq - 0.5f + 0.5f * dz * dz * expf(-2.0f * la);
        }
        out[O1 + i] = ma;
        out[O2 + i] = la;
    }
    for (int o = 32; o > 0; o >>= 1) klsum += __shfl_down(klsum, o);
    __shared__ float red[4];
    if ((threadIdx.x & 63) == 0) red[threadIdx.x >> 6] = klsum;
    __syncthreads();
    if (threadIdx.x == 0) partials[blockIdx.x] = red[0] + red[1] + red[2] + red[3];
}

__global__ void k_final(const float* __restrict__ partials, const int* __restrict__ lens,
                        float* __restrict__ out) {
    float s = 0.f;
    for (int i = threadIdx.x; i < 3072; i += 256) s += partials[i];
    for (int o = 32; o > 0; o >>= 1) s += __shfl_down(s, o);
    __shared__ float red[4];
    if ((threadIdx.x & 63) == 0) red[threadIdx.x >> 6] = s;
    __syncthreads();
    if (threadIdx.x == 0) {
        float tot = 0.f;
        for (int b = 0; b < 8; ++b) tot += (float)lens[8 + b];
        out[O3] = (red[0] + red[1] + red[2] + red[3]) / tot;
    }
}

extern "C" void kernel_launch(void* const* d_in, const int* in_sizes, int n_in,
                              void* d_out, int out_size, void* d_ws, size_t ws_size,
                              hipStream_t stream) {
    const float* z_p    = (const float*)d_in[0];
    const float* m_p    = (const float*)d_in[1];
    const float* logs_p = (const float*)d_in[2];
    const float* logs_q = (const float*)d_in[3];
    const float* tmask  = (const float*)d_in[4];
    const float* smask  = (const float*)d_in[5];
    float* out = (float*)d_out;
    char* ws = (char*)d_ws;

    float*    neg      = (float*)(ws + WS_NEG);
    float*    sarr     = (float*)(ws + WS_S);
    float*    msr      = (float*)(ws + WS_MSR);
    float*    bias     = (float*)(ws + WS_BIAS);
    uint32_t* dirs     = (uint32_t*)(ws + WS_DIRS);
    int*      idx_map  = (int*)(ws + WS_IDX);
    int*      lens     = (int*)(ws + WS_LENS);
    float*    partials = (float*)(ws + WS_PART);
    int*      cnt      = (int*)(ws + WS_PART);   // disjoint lifetime vs partials

    hipLaunchKernelGGL(k_pre,
                       dim3(PRE_NZERO + PRE_NPREP + PRE_NBIAS + PRE_NLEN + 1),
                       dim3(256), 0, stream,
                       logs_p, m_p, tmask, smask, sarr, msr, bias, lens, out, cnt);
    hipLaunchKernelGGL(k_mega,   dim3(2056),     dim3(256), 0, stream,
                       z_p, msr, sarr, bias, lens, neg, dirs, idx_map, out, cnt);
    hipLaunchKernelGGL(k_gather, dim3(3072),     dim3(256), 0, stream,
                       z_p, m_p, logs_p, logs_q, lens, idx_map, out, partials);
    hipLaunchKernelGGL(k_final,  dim3(1),        dim3(256), 0, stream, partials, lens, out);
}

// Round 14
// 500.537 us; speedup vs baseline: 1.2975x; 1.2975x over previous
//
#include <hip/hip_runtime.h>
#include <cstdint>
#include <cstddef>

// Problem shape (fixed by the reference): B=8, C=192, Tx=512, Ty=2048.
#define BB 8
#define CC 192
#define TXX 512
#define TYY 2048

#define NEG_INF (-1e9f)
#define HALF_LOG_2PI 0.9189385332046727f  // 0.5*log(2*pi)

// ---- output layout (floats, concatenated in return order) ----
#define O1 8388608
#define O2 11534336
#define O3 14680064
#define O4 14680065

// ---- workspace layout (bytes) ----
#define WS_NEG   0           // neg_cent fp32 [B,Ty,Tx]           33,554,432 B
#define WS_S     33554432    // s_p_sq_r [B,C,Tx]                  3,145,728 B
#define WS_MSR   36700160    // m_p * s  [B,C,Tx]                  3,145,728 B
#define WS_BIAS  39845888    // nc1+nc4  [B,Tx]                       16,384 B
#define WS_DIRS  39862272    // dir bits [B,Ty/4,64] dwords        1,048,576 B
#define WS_IDX   40910848    // idx_map  [B,Ty] int                   65,536 B
#define WS_LENS  40976384    // int text_len[8], spec_len[8]             64 B
#define WS_PART  40976448    // kl partials [3072] float              12,288 B

typedef float f32x4 __attribute__((ext_vector_type(4)));

// ---------------------------------------------------------------------------
// k_pre (R28): fused prep + bias + len (zero moved into k_gz to overlap
// with gemm). bias recomputes msv with the IDENTICAL expression tree as
// prep stores (bitwise-same), so no prep->bias dependency.
// ---------------------------------------------------------------------------
#define PRE_NPREP 3072
#define PRE_NBIAS 16
#define PRE_NLEN  8
__global__ __launch_bounds__(256) void k_pre(const float* __restrict__ logs_p,
                                             const float* __restrict__ m_p,
                                             const float* __restrict__ tmask,
                                             const float* __restrict__ smask,
                                             float* __restrict__ s,
                                             float* __restrict__ msr,
                                             float* __restrict__ bias,
                                             int* __restrict__ lens) {
    int blk = blockIdx.x, tid = threadIdx.x;
    if (blk < PRE_NPREP) {
        int i = blk * 256 + tid;
        float lp = logs_p[i], m = m_p[i];
        float sv = expf(-2.0f * lp);
        s[i] = sv;
        msr[i] = m * sv;
    } else if (blk < PRE_NPREP + PRE_NBIAS) {
        int i = (blk - PRE_NPREP) * 256 + tid;  // B*Tx = 4096
        int b = i >> 9, x = i & (TXX - 1);
        size_t base = (size_t)b * CC * TXX + x;
        const float* lpb = logs_p + base;
        const float* mb  = m_p + base;
        float acc = 0.f;
#pragma unroll 8
        for (int c = 0; c < CC; ++c) {
            float lp = lpb[(size_t)c * TXX];
            float m  = mb[(size_t)c * TXX];
            float msv = m * expf(-2.0f * lp);   // == msr[c] bitwise
            acc += -HALF_LOG_2PI - lp - 0.5f * m * msv;
        }
        bias[i] = acc;
    } else {
        __shared__ float red[256];
        int b = blk - (PRE_NPREP + PRE_NBIAS);
        float ts = 0.f;
        for (int i = tid; i < TXX; i += 256) ts += tmask[b * TXX + i];
        red[tid] = ts; __syncthreads();
        for (int s2 = 128; s2 > 0; s2 >>= 1) { if (tid < s2) red[tid] += red[tid + s2]; __syncthreads(); }
        if (tid == 0) lens[b] = (int)(red[0] + 0.5f);
        __syncthreads();
        float ss = 0.f;
        for (int i = tid; i < TYY; i += 256) ss += smask[b * TYY + i];
        red[tid] = ss; __syncthreads();
        for (int s2 = 128; s2 > 0; s2 >>= 1) { if (tid < s2) red[tid] += red[tid + s2]; __syncthreads(); }
        if (tid == 0) lens[8 + b] = (int)(red[0] + 0.5f);
    }
}

// ---------------------------------------------------------------------------
// k_gz (R28): zero blocks (0..511) + proven 64x64 gemm (512..2559).
// Zero blocks dispatch FIRST, retire in ~3us, and their ~59MB of HBM writes
// hide under gemm's compute phase (no sync needed: disjoint outputs; kernel
// boundary before k_bwd's scatter). Gemm block mapping preserves the
// original (x fastest, then t, then b) dispatch order exactly.
// ---------------------------------------------------------------------------
#define GZ_NZERO 512
__global__ __launch_bounds__(256) void k_gz(const float* __restrict__ z,
                                            const float* __restrict__ msr,
                                            const float* __restrict__ sarr,
                                            const float* __restrict__ bias,
                                            const int* __restrict__ lens,
                                            float* __restrict__ neg,
                                            float* __restrict__ out) {
    int id = blockIdx.x, tid = threadIdx.x;
    if (id < GZ_NZERO) {
        int64_t i = (int64_t)id * 256 + tid;
        const int64_t n4 = (int64_t)BB * TYY * TXX / 4;
        float4 z4 = make_float4(0.f, 0.f, 0.f, 0.f);
        float4* p4 = (float4*)out;
        for (int64_t k = i; k < n4; k += (int64_t)GZ_NZERO * 256) p4[k] = z4;
        if (i < BB * TXX) out[O4 + i] = 0.0f;
        return;
    }
    int gid = id - GZ_NZERO;
    int x0 = (gid & 7) * 64, t0 = ((gid >> 3) & 31) * 64, b = gid >> 8;
    if (x0 >= lens[b] || t0 >= lens[8 + b]) return;   // masked tile

    __shared__ float Zs[16][68], Ms[16][68], Ss[16][68];  // +4 pad
    int tx = tid & 15, ty = tid >> 4;
    const float* zb = z    + (size_t)b * CC * TYY;
    const float* mb = msr  + (size_t)b * CC * TXX;
    const float* sb = sarr + (size_t)b * CC * TXX;
    int lr = tid >> 4, lc = (tid & 15) * 4;
    float acc[4][4] = {};
    for (int k0 = 0; k0 < CC; k0 += 16) {
        float4 zv = *(const float4*)(zb + (size_t)(k0 + lr) * TYY + t0 + lc);
        float4 mv = *(const float4*)(mb + (size_t)(k0 + lr) * TXX + x0 + lc);
        float4 sv = *(const float4*)(sb + (size_t)(k0 + lr) * TXX + x0 + lc);
        __syncthreads();
        *(float4*)&Zs[lr][lc] = zv;
        *(float4*)&Ms[lr][lc] = mv;
        *(float4*)&Ss[lr][lc] = sv;
        __syncthreads();
#pragma unroll
        for (int k = 0; k < 16; ++k) {
            float4 a4  = *(const float4*)&Zs[k][ty * 4];
            float4 bm4 = *(const float4*)&Ms[k][tx * 4];
            float4 bs4 = *(const float4*)&Ss[k][tx * 4];
            float av[4]  = {a4.x, a4.y, a4.z, a4.w};
            float bmv[4] = {bm4.x, bm4.y, bm4.z, bm4.w};
            float bsv[4] = {bs4.x, bs4.y, bs4.z, bs4.w};
#pragma unroll
            for (int i2 = 0; i2 < 4; ++i2) {
                float a2 = -0.5f * av[i2] * av[i2];
#pragma unroll
                for (int j = 0; j < 4; ++j)
                    acc[i2][j] += av[i2] * bmv[j] + a2 * bsv[j];
            }
        }
    }
    float4 b4 = *(const float4*)(bias + b * TXX + x0 + tx * 4);
    float bv[4] = {b4.x, b4.y, b4.z, b4.w};
#pragma unroll
    for (int i2 = 0; i2 < 4; ++i2) {
        int t = t0 + ty * 4 + i2;
        float4 o;
        o.x = acc[i2][0] + bv[0]; o.y = acc[i2][1] + bv[1];
        o.z = acc[i2][2] + bv[2]; o.w = acc[i2][3] + bv[3];
        *(float4*)(neg + ((size_t)b * TYY + t) * TXX + x0 + tx * 4) = o;
    }
}

// ---------------------------------------------------------------------------
// MAS forward pass v5 (proven best: 187.5 us, 3 containers). UNTOUCHED.
// ---------------------------------------------------------------------------
#define GLOAD4(DST, PTR, OFF)                                             \
    asm volatile("global_load_dwordx4 %0, %1, off offset:" #OFF           \
                 : "=v"(DST) : "v"(PTR) : "memory")

#define GLOADD(DST, PTR)                                                  \
    asm volatile("global_load_dword %0, %1, off"                          \
                 : "=v"(DST) : "v"(PTR) : "memory")

#define WAIT_VM(N) do {                                                   \
    asm volatile("s_waitcnt vmcnt(" #N ")" ::: "memory");                 \
    __builtin_amdgcn_sched_barrier(0);                                    \
} while (0)

#define LOADG(DST, G) do {                                                \
    const char* p0_ = (const char*)nc4 + (size_t)(G) * 16384 + lane * 32; \
    const char* p2_ = p0_ + 4096;                                         \
    const char* p4_ = p0_ + 8192;                                         \
    const char* p6_ = p0_ + 12288;                                        \
    GLOAD4(DST[0],  p0_, 0);    GLOAD4(DST[1],  p0_, 16);                 \
    GLOAD4(DST[2],  p0_, 2048); GLOAD4(DST[3],  p0_, 2064);               \
    GLOAD4(DST[4],  p2_, 0);    GLOAD4(DST[5],  p2_, 16);                 \
    GLOAD4(DST[6],  p2_, 2048); GLOAD4(DST[7],  p2_, 2064);               \
    GLOAD4(DST[8],  p4_, 0);    GLOAD4(DST[9],  p4_, 16);                 \
    GLOAD4(DST[10], p4_, 2048); GLOAD4(DST[11], p4_, 2064);               \
    GLOAD4(DST[12], p6_, 0);    GLOAD4(DST[13], p6_, 16);                 \
    GLOAD4(DST[14], p6_, 2048); GLOAD4(DST[15], p6_, 2064);               \
} while (0)

#define DPROW(CUR, YB, R) do {                                                \
    int y_ = (YB) + (R);                                                      \
    float s0_ = CUR[2*(R)][0],   s1_ = CUR[2*(R)][1];                         \
    float s2_ = CUR[2*(R)][2],   s3_ = CUR[2*(R)][3];                         \
    float s4_ = CUR[2*(R)+1][0], s5_ = CUR[2*(R)+1][1];                       \
    float s6_ = CUR[2*(R)+1][2], s7_ = CUR[2*(R)+1][3];                       \
    unsigned d_ = 0;                                                          \
    if (y_ == 0) {                                                            \
        if (lane == 0) v[0] = s0_;   /* only x==0 scored on row 0 */          \
    } else {                                                                  \
        float pl_ = __int_as_float(__builtin_amdgcn_update_dpp(               \
            0, __float_as_int(v[7]), 0x138, 0xF, 0xF, false));                \
        if (lane == 0) pl_ = NEG_INF;                                         \
        float n0_ = s0_ + fmaxf(v[0], pl_);  if (pl_  > v[0]) d_ |= 1u;       \
        float n1_ = s1_ + fmaxf(v[1], v[0]); if (v[0] > v[1]) d_ |= 2u;       \
        float n2_ = s2_ + fmaxf(v[2], v[1]); if (v[1] > v[2]) d_ |= 4u;       \
        float n3_ = s3_ + fmaxf(v[3], v[2]); if (v[2] > v[3]) d_ |= 8u;       \
        float n4_ = s4_ + fmaxf(v[4], v[3]); if (v[3] > v[4]) d_ |= 16u;      \
        float n5_ = s5_ + fmaxf(v[5], v[4]); if (v[4] > v[5]) d_ |= 32u;      \
        float n6_ = s6_ + fmaxf(v[6], v[5]); if (v[5] > v[6]) d_ |= 64u;      \
        float n7_ = s7_ + fmaxf(v[7], v[6]); if (v[6] > v[7]) d_ |= 128u;     \
        v[0] = n0_; v[1] = n1_; v[2] = n2_; v[3] = n3_;                       \
        v[4] = n4_; v[5] = n5_; v[6] = n6_; v[7] = n7_;                       \
    }                                                                         \
    unsigned t_ = (unsigned)(y_ - 8 * lane);                                  \
    if (t_ < 8u) d_ |= 1u << t_;          /* fold x==y for backtrack */       \
    acc |= d_ << (((R) & 3) * 8);                                             \
    if (((R) & 3) == 3) { db32[(y_ >> 2) * 64 + lane] = acc; acc = 0; }       \
} while (0)

#define FWD_ITER(G, CUR, NXT) do {                                \
    int g_ = (G);                                                 \
    if (g_ + 2 < ng) {                                            \
        LOADG(NXT, g_ + 2);  /* prefetch 2 ahead */               \
        WAIT_VM(32);                                              \
    } else if (g_ + 1 < ng) {                                     \
        WAIT_VM(16);                                              \
    } else {                                                      \
        WAIT_VM(0);                                               \
    }                                                             \
    int yb_ = 8 * g_;                                             \
    DPROW(CUR, yb_, 0); DPROW(CUR, yb_, 1);                       \
    DPROW(CUR, yb_, 2); DPROW(CUR, yb_, 3);                       \
    DPROW(CUR, yb_, 4); DPROW(CUR, yb_, 5);                       \
    DPROW(CUR, yb_, 6); DPROW(CUR, yb_, 7);                       \
} while (0)

__global__ __launch_bounds__(64, 1) void k_fwd(const float* __restrict__ neg,
                                               const int* __restrict__ lens,
                                               uint32_t* __restrict__ dirs) {
    int b = blockIdx.x, lane = threadIdx.x;
    const float* nc4 = neg + (size_t)b * TYY * TXX;   // byte math in LOADG
    uint32_t* db32 = dirs + (size_t)b * (TYY / 4) * 64;
    int slen = lens[8 + b];
    int ng = (slen + 7) >> 3;    // 192..256 (slen >= 1536)

    float v[8];
#pragma unroll
    for (int j = 0; j < 8; ++j) v[j] = NEG_INF;
    unsigned acc = 0;

    f32x4 bufA[16], bufB[16], bufC[16];  // 3 groups in flight, asm-pinned
    LOADG(bufA, 0);
    LOADG(bufB, 1);

    for (int p = 0; p < ng; p += 3) {
        FWD_ITER(p, bufA, bufC);
        if (p + 1 < ng) FWD_ITER(p + 1, bufB, bufA);
        if (p + 2 < ng) FWD_ITER(p + 2, bufC, bufB);
    }
}

// ---------------------------------------------------------------------------
// MAS backtrack v3 (R28): TRULY deferred packing.
// R26's LOADW packed immediately after its loads -> the compiler's waitcnt
// sat BEFORE the 32-step chain, exposing full L2-miss latency per slab
// (~40-60us total). v3 carries 12 RAW dwords: issue next slab's asm-pinned
// loads -> sched_barrier -> run the chain (~256cy, covers latency) ->
// vmcnt(0) (loads landed long ago) -> pack -> stores. Window algebra is
// R26's verified version (wbn from idx-32; s = clamp(w0-wb,0,1)).
// Scatter + duration fused in the store step (R26-proven).
// ---------------------------------------------------------------------------
#define RAWLD(NR, WB, QROW) do {                                          \
    const uint32_t* p_ = db32 + (QROW) + 4 * (WB);                        \
    GLOADD(NR[0],  (p_ + 0));  GLOADD(NR[1],  (p_ + 1));                  \
    GLOADD(NR[2],  (p_ + 2));  GLOADD(NR[3],  (p_ + 3));                  \
    GLOADD(NR[4],  (p_ + 4));  GLOADD(NR[5],  (p_ + 5));                  \
    GLOADD(NR[6],  (p_ + 6));  GLOADD(NR[7],  (p_ + 7));                  \
    GLOADD(NR[8],  (p_ + 8));  GLOADD(NR[9],  (p_ + 9));                  \
    GLOADD(NR[10], (p_ + 10)); GLOADD(NR[11], (p_ + 11));                 \
} while (0)

#define PACKW(W0, W1, W2, NR, BOFF) do {                                  \
    W0 = ((NR[0]>>(BOFF))&0xffu)        | (((NR[1]>>(BOFF))&0xffu)<<8) |  \
         (((NR[2]>>(BOFF))&0xffu)<<16)  | (((NR[3]>>(BOFF))&0xffu)<<24);  \
    W1 = ((NR[4]>>(BOFF))&0xffu)        | (((NR[5]>>(BOFF))&0xffu)<<8) |  \
         (((NR[6]>>(BOFF))&0xffu)<<16)  | (((NR[7]>>(BOFF))&0xffu)<<24);  \
    W2 = ((NR[8]>>(BOFF))&0xffu)        | (((NR[9]>>(BOFF))&0xffu)<<8) |  \
         (((NR[10]>>(BOFF))&0xffu)<<16) | (((NR[11]>>(BOFF))&0xffu)<<24); \
} while (0)

__global__ __launch_bounds__(64, 1) void k_bwd(const int* __restrict__ lens,
                                               const uint32_t* __restrict__ dirs,
                                               int* __restrict__ idx_map,
                                               float* __restrict__ out) {
    int b = blockIdx.x, lane = threadIdx.x;
    const uint32_t* db32 = dirs + (size_t)b * (TYY / 4) * 64;
    int tlen = lens[b], slen = lens[8 + b];

    int idx = tlen - 1;
    int y0 = slen - 1;
    int wb;
    uint32_t W0 = 0, W1 = 0, W2 = 0;
    {   // prologue: slab-0 window (one unavoidable stall)
        int yy = y0 - lane; if (yy < 0) yy = 0;
        int qrow = (yy >> 2) * 64, boff = (yy & 3) * 8;
        int t = (idx >> 5) - 1; if (t < 0) t = 0; if (t > 13) t = 13;
        wb = t;
        uint32_t R[12];
        if (lane < 32) {
            RAWLD(R, wb, qrow);
            asm volatile("s_waitcnt vmcnt(0)" ::: "memory");
            __builtin_amdgcn_sched_barrier(0);
            PACKW(W0, W1, W2, R, boff);
        }
    }
    while (y0 >= 0) {
        int w0 = (idx >> 5) - 1; if (w0 < 0) w0 = 0; if (w0 > 14) w0 = 14;
        int s = w0 - wb; if (s < 0) s = 0; if (s > 1) s = 1;
        uint32_t lo = s ? W1 : W0;
        uint32_t hi = s ? W2 : W1;
        int base = (wb + s) << 5;
        // ---- issue next slab's RAW loads (latency hides under the chain) --
        uint32_t N[12];
        int idxm = idx - 32; if (idxm < 0) idxm = 0;
        int wbn = (idxm >> 5) - 1; if (wbn < 0) wbn = 0; if (wbn > 13) wbn = 13;
        int yn = y0 - 32 - lane; if (yn < 0) yn = 0;
        int qn = (yn >> 2) * 64, bn = (yn & 3) * 8;
        if (lane < 32) RAWLD(N, wbn, qn);
        __builtin_amdgcn_sched_barrier(0);
        // ---- 32-step chain ----
        int nsteps = (y0 + 1 < 32) ? y0 + 1 : 32;
        int cap = 0;
#pragma unroll
        for (int j = 0; j < 32; ++j) {
            if (lane == j) cap = idx;
            uint32_t l = (uint32_t)__builtin_amdgcn_readlane((int)lo, j);
            uint32_t h = (uint32_t)__builtin_amdgcn_readlane((int)hi, j);
            int bp = idx - base;              // 0..63 within slab
            uint32_t word = (bp & 32) ? h : l;
            idx -= (int)((word >> (bp & 31)) & 1u);
        }
        __builtin_amdgcn_sched_barrier(0);
        asm volatile("s_waitcnt vmcnt(0)" ::: "memory");   // N landed
        __builtin_amdgcn_sched_barrier(0);
        PACKW(W0, W1, W2, N, bn);
        wb = wbn;
        if (lane < nsteps) {
            int y = y0 - lane;
            idx_map[b * TYY + y] = cap;
            out[((size_t)(b * TYY + y)) * TXX + cap] = 1.0f;       // scatter
            atomicAdd(&out[O4 + b * TXX + cap], 1.0f);             // duration
        }
        y0 -= 32;
    }
}

// Gather m_p/logs_p onto spec frames via idx_map; fused KL partial sums.
__global__ __launch_bounds__(256) void k_gather(const float* __restrict__ z_p,
                                                const float* __restrict__ m_p,
                                                const float* __restrict__ logs_p,
                                                const float* __restrict__ logs_q,
                                                const int* __restrict__ lens,
                                                const int* __restrict__ idx_map,
                                                float* __restrict__ out,
                                                float* __restrict__ partials) {
    const int S = BB * CC * TYY / 4;
    int base = blockIdx.x * 256 + threadIdx.x;
    float klsum = 0.f;
#pragma unroll
    for (int r = 0; r < 4; ++r) {
        int i = base + r * S;
        int t = i & (TYY - 1);
        int bc = i >> 11;
        int b = bc / CC;
        float ma = 0.f, la = 0.f;
        if (t < lens[8 + b]) {
            int x = idx_map[b * TYY + t];
            size_t off = (size_t)bc * TXX + x;
            ma = m_p[off];
            la = logs_p[off];
            float zv = z_p[i], lq = logs_q[i];
            float dz = zv - ma;
            klsum += la - lq - 0.5f + 0.5f * dz * dz * expf(-2.0f * la);
        }
        out[O1 + i] = ma;
        out[O2 + i] = la;
    }
    for (int o = 32; o > 0; o >>= 1) klsum += __shfl_down(klsum, o);
    __shared__ float red[4];
    if ((threadIdx.x & 63) == 0) red[threadIdx.x >> 6] = klsum;
    __syncthreads();
    if (threadIdx.x == 0) partials[blockIdx.x] = red[0] + red[1] + red[2] + red[3];
}

__global__ void k_final(const float* __restrict__ partials, const int* __restrict__ lens,
                        float* __restrict__ out) {
    float s = 0.f;
    for (int i = threadIdx.x; i < 3072; i += 256) s += partials[i];
    for (int o = 32; o > 0; o >>= 1) s += __shfl_down(s, o);
    __shared__ float red[4];
    if ((threadIdx.x & 63) == 0) red[threadIdx.x >> 6] = s;
    __syncthreads();
    if (threadIdx.x == 0) {
        float tot = 0.f;
        for (int b = 0; b < 8; ++b) tot += (float)lens[8 + b];
        out[O3] = (red[0] + red[1] + red[2] + red[3]) / tot;
    }
}

extern "C" void kernel_launch(void* const* d_in, const int* in_sizes, int n_in,
                              void* d_out, int out_size, void* d_ws, size_t ws_size,
                              hipStream_t stream) {
    const float* z_p    = (const float*)d_in[0];
    const float* m_p    = (const float*)d_in[1];
    const float* logs_p = (const float*)d_in[2];
    const float* logs_q = (const float*)d_in[3];
    const float* tmask  = (const float*)d_in[4];
    const float* smask  = (const float*)d_in[5];
    float* out = (float*)d_out;
    char* ws = (char*)d_ws;

    float*    neg      = (float*)(ws + WS_NEG);
    float*    sarr     = (float*)(ws + WS_S);
    float*    msr      = (float*)(ws + WS_MSR);
    float*    bias     = (float*)(ws + WS_BIAS);
    uint32_t* dirs     = (uint32_t*)(ws + WS_DIRS);
    int*      idx_map  = (int*)(ws + WS_IDX);
    int*      lens     = (int*)(ws + WS_LENS);
    float*    partials = (float*)(ws + WS_PART);

    hipLaunchKernelGGL(k_pre,    dim3(PRE_NPREP + PRE_NBIAS + PRE_NLEN),
                       dim3(256), 0, stream,
                       logs_p, m_p, tmask, smask, sarr, msr, bias, lens);
    hipLaunchKernelGGL(k_gz,     dim3(GZ_NZERO + 2048), dim3(256), 0, stream,
                       z_p, msr, sarr, bias, lens, neg, out);
    hipLaunchKernelGGL(k_fwd,    dim3(8),        dim3(64),  0, stream, neg, lens, dirs);
    hipLaunchKernelGGL(k_bwd,    dim3(8),        dim3(64),  0, stream, lens, dirs, idx_map, out);
    hipLaunchKernelGGL(k_gather, dim3(3072),     dim3(256), 0, stream,
                       z_p, m_p, logs_p, logs_q, lens, idx_map, out, partials);
    hipLaunchKernelGGL(k_final,  dim3(1),        dim3(256), 0, stream, partials, lens, out);
}

// Round 15
// 488.371 us; speedup vs baseline: 1.3298x; 1.0249x over previous
//
#include <hip/hip_runtime.h>
#include <cstdint>
#include <cstddef>

// Problem shape (fixed by the reference): B=8, C=192, Tx=512, Ty=2048.
#define BB 8
#define CC 192
#define TXX 512
#define TYY 2048

#define NEG_INF (-1e9f)
#define HALF_LOG_2PI 0.9189385332046727f  // 0.5*log(2*pi)

// ---- output layout (floats, concatenated in return order) ----
#define O1 8388608
#define O2 11534336
#define O3 14680064
#define O4 14680065

// ---- workspace layout (bytes) ----
#define WS_NEG   0           // neg_cent fp32 [B,Ty,Tx]           33,554,432 B
#define WS_S     33554432    // s_p_sq_r [B,C,Tx]                  3,145,728 B
#define WS_MSR   36700160    // m_p * s  [B,C,Tx]                  3,145,728 B
#define WS_BIAS  39845888    // nc1+nc4  [B,Tx]                       16,384 B
#define WS_DIRS  39862272    // dir bits [B,Ty/4,64] dwords        1,048,576 B
#define WS_IDX   40910848    // idx_map  [B,Ty] int                   65,536 B
#define WS_LENS  40976384    // int text_len[8], spec_len[8]             64 B
#define WS_PART  40976448    // kl partials [3072] float              12,288 B

typedef float f32x4 __attribute__((ext_vector_type(4)));

// ---------------------------------------------------------------------------
// k_pre (R28): fused prep + bias + len (zero lives in k_gz to overlap with
// gemm). bias recomputes msv with the IDENTICAL expression tree as prep
// stores (bitwise-same), so no prep->bias dependency.
// ---------------------------------------------------------------------------
#define PRE_NPREP 3072
#define PRE_NBIAS 16
#define PRE_NLEN  8
__global__ __launch_bounds__(256) void k_pre(const float* __restrict__ logs_p,
                                             const float* __restrict__ m_p,
                                             const float* __restrict__ tmask,
                                             const float* __restrict__ smask,
                                             float* __restrict__ s,
                                             float* __restrict__ msr,
                                             float* __restrict__ bias,
                                             int* __restrict__ lens) {
    int blk = blockIdx.x, tid = threadIdx.x;
    if (blk < PRE_NPREP) {
        int i = blk * 256 + tid;
        float lp = logs_p[i], m = m_p[i];
        float sv = expf(-2.0f * lp);
        s[i] = sv;
        msr[i] = m * sv;
    } else if (blk < PRE_NPREP + PRE_NBIAS) {
        int i = (blk - PRE_NPREP) * 256 + tid;  // B*Tx = 4096
        int b = i >> 9, x = i & (TXX - 1);
        size_t base = (size_t)b * CC * TXX + x;
        const float* lpb = logs_p + base;
        const float* mb  = m_p + base;
        float acc = 0.f;
#pragma unroll 8
        for (int c = 0; c < CC; ++c) {
            float lp = lpb[(size_t)c * TXX];
            float m  = mb[(size_t)c * TXX];
            float msv = m * expf(-2.0f * lp);   // == msr[c] bitwise
            acc += -HALF_LOG_2PI - lp - 0.5f * m * msv;
        }
        bias[i] = acc;
    } else {
        __shared__ float red[256];
        int b = blk - (PRE_NPREP + PRE_NBIAS);
        float ts = 0.f;
        for (int i = tid; i < TXX; i += 256) ts += tmask[b * TXX + i];
        red[tid] = ts; __syncthreads();
        for (int s2 = 128; s2 > 0; s2 >>= 1) { if (tid < s2) red[tid] += red[tid + s2]; __syncthreads(); }
        if (tid == 0) lens[b] = (int)(red[0] + 0.5f);
        __syncthreads();
        float ss = 0.f;
        for (int i = tid; i < TYY; i += 256) ss += smask[b * TYY + i];
        red[tid] = ss; __syncthreads();
        for (int s2 = 128; s2 > 0; s2 >>= 1) { if (tid < s2) red[tid] += red[tid + s2]; __syncthreads(); }
        if (tid == 0) lens[8 + b] = (int)(red[0] + 0.5f);
    }
}

// ---------------------------------------------------------------------------
// k_gz (R29): zero blocks (0..511) + 64x64 gemm with REGISTER DOUBLE-
// BUFFERED staging (512..2559).
// R28 ledger: gemm ~100-150us vs 32-41us FMA floor. Old loop exposed the
// next K-step's ~500cy global-load latency after BOTH barriers on every one
// of 12 K-steps (all 8 blocks/CU stall in lockstep at the same phase).
// R29 rotates: preload k0=0; loop { sync; write LDS; sync; issue load
// k0+16; compute } -- next load's latency hides under the ~1000cy FMA
// block. FMA order per output unchanged -> bitwise-identical neg.
// Zero blocks dispatch first and their HBM writes hide under gemm compute.
// ---------------------------------------------------------------------------
#define GZ_NZERO 512
__global__ __launch_bounds__(256) void k_gz(const float* __restrict__ z,
                                            const float* __restrict__ msr,
                                            const float* __restrict__ sarr,
                                            const float* __restrict__ bias,
                                            const int* __restrict__ lens,
                                            float* __restrict__ neg,
                                            float* __restrict__ out) {
    int id = blockIdx.x, tid = threadIdx.x;
    if (id < GZ_NZERO) {
        int64_t i = (int64_t)id * 256 + tid;
        const int64_t n4 = (int64_t)BB * TYY * TXX / 4;
        float4 z4 = make_float4(0.f, 0.f, 0.f, 0.f);
        float4* p4 = (float4*)out;
        for (int64_t k = i; k < n4; k += (int64_t)GZ_NZERO * 256) p4[k] = z4;
        if (i < BB * TXX) out[O4 + i] = 0.0f;
        return;
    }
    int gid = id - GZ_NZERO;
    int x0 = (gid & 7) * 64, t0 = ((gid >> 3) & 31) * 64, b = gid >> 8;
    if (x0 >= lens[b] || t0 >= lens[8 + b]) return;   // masked tile

    __shared__ float Zs[16][68], Ms[16][68], Ss[16][68];  // +4 pad
    int tx = tid & 15, ty = tid >> 4;
    const float* zb = z    + (size_t)b * CC * TYY;
    const float* mb = msr  + (size_t)b * CC * TXX;
    const float* sb = sarr + (size_t)b * CC * TXX;
    int lr = tid >> 4, lc = (tid & 15) * 4;
    float acc[4][4] = {};
    // preload K-step 0
    float4 zv = *(const float4*)(zb + (size_t)lr * TYY + t0 + lc);
    float4 mv = *(const float4*)(mb + (size_t)lr * TXX + x0 + lc);
    float4 sv = *(const float4*)(sb + (size_t)lr * TXX + x0 + lc);
    for (int k0 = 0; k0 < CC; k0 += 16) {
        __syncthreads();
        *(float4*)&Zs[lr][lc] = zv;
        *(float4*)&Ms[lr][lc] = mv;
        *(float4*)&Ss[lr][lc] = sv;
        __syncthreads();
        if (k0 + 16 < CC) {   // issue next K-step's loads BEFORE compute
            zv = *(const float4*)(zb + (size_t)(k0 + 16 + lr) * TYY + t0 + lc);
            mv = *(const float4*)(mb + (size_t)(k0 + 16 + lr) * TXX + x0 + lc);
            sv = *(const float4*)(sb + (size_t)(k0 + 16 + lr) * TXX + x0 + lc);
        }
#pragma unroll
        for (int k = 0; k < 16; ++k) {
            float4 a4  = *(const float4*)&Zs[k][ty * 4];
            float4 bm4 = *(const float4*)&Ms[k][tx * 4];
            float4 bs4 = *(const float4*)&Ss[k][tx * 4];
            float av[4]  = {a4.x, a4.y, a4.z, a4.w};
            float bmv[4] = {bm4.x, bm4.y, bm4.z, bm4.w};
            float bsv[4] = {bs4.x, bs4.y, bs4.z, bs4.w};
#pragma unroll
            for (int i2 = 0; i2 < 4; ++i2) {
                float a2 = -0.5f * av[i2] * av[i2];
#pragma unroll
                for (int j = 0; j < 4; ++j)
                    acc[i2][j] += av[i2] * bmv[j] + a2 * bsv[j];
            }
        }
    }
    float4 b4 = *(const float4*)(bias + b * TXX + x0 + tx * 4);
    float bv[4] = {b4.x, b4.y, b4.z, b4.w};
#pragma unroll
    for (int i2 = 0; i2 < 4; ++i2) {
        int t = t0 + ty * 4 + i2;
        float4 o;
        o.x = acc[i2][0] + bv[0]; o.y = acc[i2][1] + bv[1];
        o.z = acc[i2][2] + bv[2]; o.w = acc[i2][3] + bv[3];
        *(float4*)(neg + ((size_t)b * TYY + t) * TXX + x0 + tx * 4) = o;
    }
}

// ---------------------------------------------------------------------------
// MAS forward pass v5 (proven best: 187.2 us, 4 containers). UNTOUCHED.
// ---------------------------------------------------------------------------
#define GLOAD4(DST, PTR, OFF)                                             \
    asm volatile("global_load_dwordx4 %0, %1, off offset:" #OFF           \
                 : "=v"(DST) : "v"(PTR) : "memory")

#define GLOADD(DST, PTR)                                                  \
    asm volatile("global_load_dword %0, %1, off"                          \
                 : "=v"(DST) : "v"(PTR) : "memory")

#define WAIT_VM(N) do {                                                   \
    asm volatile("s_waitcnt vmcnt(" #N ")" ::: "memory");                 \
    __builtin_amdgcn_sched_barrier(0);                                    \
} while (0)

#define LOADG(DST, G) do {                                                \
    const char* p0_ = (const char*)nc4 + (size_t)(G) * 16384 + lane * 32; \
    const char* p2_ = p0_ + 4096;                                         \
    const char* p4_ = p0_ + 8192;                                         \
    const char* p6_ = p0_ + 12288;                                        \
    GLOAD4(DST[0],  p0_, 0);    GLOAD4(DST[1],  p0_, 16);                 \
    GLOAD4(DST[2],  p0_, 2048); GLOAD4(DST[3],  p0_, 2064);               \
    GLOAD4(DST[4],  p2_, 0);    GLOAD4(DST[5],  p2_, 16);                 \
    GLOAD4(DST[6],  p2_, 2048); GLOAD4(DST[7],  p2_, 2064);               \
    GLOAD4(DST[8],  p4_, 0);    GLOAD4(DST[9],  p4_, 16);                 \
    GLOAD4(DST[10], p4_, 2048); GLOAD4(DST[11], p4_, 2064);               \
    GLOAD4(DST[12], p6_, 0);    GLOAD4(DST[13], p6_, 16);                 \
    GLOAD4(DST[14], p6_, 2048); GLOAD4(DST[15], p6_, 2064);               \
} while (0)

#define DPROW(CUR, YB, R) do {                                                \
    int y_ = (YB) + (R);                                                      \
    float s0_ = CUR[2*(R)][0],   s1_ = CUR[2*(R)][1];                         \
    float s2_ = CUR[2*(R)][2],   s3_ = CUR[2*(R)][3];                         \
    float s4_ = CUR[2*(R)+1][0], s5_ = CUR[2*(R)+1][1];                       \
    float s6_ = CUR[2*(R)+1][2], s7_ = CUR[2*(R)+1][3];                       \
    unsigned d_ = 0;                                                          \
    if (y_ == 0) {                                                            \
        if (lane == 0) v[0] = s0_;   /* only x==0 scored on row 0 */          \
    } else {                                                                  \
        float pl_ = __int_as_float(__builtin_amdgcn_update_dpp(               \
            0, __float_as_int(v[7]), 0x138, 0xF, 0xF, false));                \
        if (lane == 0) pl_ = NEG_INF;                                         \
        float n0_ = s0_ + fmaxf(v[0], pl_);  if (pl_  > v[0]) d_ |= 1u;       \
        float n1_ = s1_ + fmaxf(v[1], v[0]); if (v[0] > v[1]) d_ |= 2u;       \
        float n2_ = s2_ + fmaxf(v[2], v[1]); if (v[1] > v[2]) d_ |= 4u;       \
        float n3_ = s3_ + fmaxf(v[3], v[2]); if (v[2] > v[3]) d_ |= 8u;       \
        float n4_ = s4_ + fmaxf(v[4], v[3]); if (v[3] > v[4]) d_ |= 16u;      \
        float n5_ = s5_ + fmaxf(v[5], v[4]); if (v[4] > v[5]) d_ |= 32u;      \
        float n6_ = s6_ + fmaxf(v[6], v[5]); if (v[5] > v[6]) d_ |= 64u;      \
        float n7_ = s7_ + fmaxf(v[7], v[6]); if (v[6] > v[7]) d_ |= 128u;     \
        v[0] = n0_; v[1] = n1_; v[2] = n2_; v[3] = n3_;                       \
        v[4] = n4_; v[5] = n5_; v[6] = n6_; v[7] = n7_;                       \
    }                                                                         \
    unsigned t_ = (unsigned)(y_ - 8 * lane);                                  \
    if (t_ < 8u) d_ |= 1u << t_;          /* fold x==y for backtrack */       \
    acc |= d_ << (((R) & 3) * 8);                                             \
    if (((R) & 3) == 3) { db32[(y_ >> 2) * 64 + lane] = acc; acc = 0; }       \
} while (0)

#define FWD_ITER(G, CUR, NXT) do {                                \
    int g_ = (G);                                                 \
    if (g_ + 2 < ng) {                                            \
        LOADG(NXT, g_ + 2);  /* prefetch 2 ahead */               \
        WAIT_VM(32);                                              \
    } else if (g_ + 1 < ng) {                                     \
        WAIT_VM(16);                                              \
    } else {                                                      \
        WAIT_VM(0);                                               \
    }                                                             \
    int yb_ = 8 * g_;                                             \
    DPROW(CUR, yb_, 0); DPROW(CUR, yb_, 1);                       \
    DPROW(CUR, yb_, 2); DPROW(CUR, yb_, 3);                       \
    DPROW(CUR, yb_, 4); DPROW(CUR, yb_, 5);                       \
    DPROW(CUR, yb_, 6); DPROW(CUR, yb_, 7);                       \
} while (0)

__global__ __launch_bounds__(64, 1) void k_fwd(const float* __restrict__ neg,
                                               const int* __restrict__ lens,
                                               uint32_t* __restrict__ dirs) {
    int b = blockIdx.x, lane = threadIdx.x;
    const float* nc4 = neg + (size_t)b * TYY * TXX;   // byte math in LOADG
    uint32_t* db32 = dirs + (size_t)b * (TYY / 4) * 64;
    int slen = lens[8 + b];
    int ng = (slen + 7) >> 3;    // 192..256 (slen >= 1536)

    float v[8];
#pragma unroll
    for (int j = 0; j < 8; ++j) v[j] = NEG_INF;
    unsigned acc = 0;

    f32x4 bufA[16], bufB[16], bufC[16];  // 3 groups in flight, asm-pinned
    LOADG(bufA, 0);
    LOADG(bufB, 1);

    for (int p = 0; p < ng; p += 3) {
        FWD_ITER(p, bufA, bufC);
        if (p + 1 < ng) FWD_ITER(p + 1, bufB, bufA);
        if (p + 2 < ng) FWD_ITER(p + 2, bufC, bufB);
    }
}

// ---------------------------------------------------------------------------
// MAS backtrack v3 (R28, proven): truly deferred packing; raw loads issued
// before the 32-step chain, packed after vmcnt(0) once latency is covered.
// Scatter + duration fused in the store step.
// ---------------------------------------------------------------------------
#define RAWLD(NR, WB, QROW) do {                                          \
    const uint32_t* p_ = db32 + (QROW) + 4 * (WB);                        \
    GLOADD(NR[0],  (p_ + 0));  GLOADD(NR[1],  (p_ + 1));                  \
    GLOADD(NR[2],  (p_ + 2));  GLOADD(NR[3],  (p_ + 3));                  \
    GLOADD(NR[4],  (p_ + 4));  GLOADD(NR[5],  (p_ + 5));                  \
    GLOADD(NR[6],  (p_ + 6));  GLOADD(NR[7],  (p_ + 7));                  \
    GLOADD(NR[8],  (p_ + 8));  GLOADD(NR[9],  (p_ + 9));                  \
    GLOADD(NR[10], (p_ + 10)); GLOADD(NR[11], (p_ + 11));                 \
} while (0)

#define PACKW(W0, W1, W2, NR, BOFF) do {                                  \
    W0 = ((NR[0]>>(BOFF))&0xffu)        | (((NR[1]>>(BOFF))&0xffu)<<8) |  \
         (((NR[2]>>(BOFF))&0xffu)<<16)  | (((NR[3]>>(BOFF))&0xffu)<<24);  \
    W1 = ((NR[4]>>(BOFF))&0xffu)        | (((NR[5]>>(BOFF))&0xffu)<<8) |  \
         (((NR[6]>>(BOFF))&0xffu)<<16)  | (((NR[7]>>(BOFF))&0xffu)<<24);  \
    W2 = ((NR[8]>>(BOFF))&0xffu)        | (((NR[9]>>(BOFF))&0xffu)<<8) |  \
         (((NR[10]>>(BOFF))&0xffu)<<16) | (((NR[11]>>(BOFF))&0xffu)<<24); \
} while (0)

__global__ __launch_bounds__(64, 1) void k_bwd(const int* __restrict__ lens,
                                               const uint32_t* __restrict__ dirs,
                                               int* __restrict__ idx_map,
                                               float* __restrict__ out) {
    int b = blockIdx.x, lane = threadIdx.x;
    const uint32_t* db32 = dirs + (size_t)b * (TYY / 4) * 64;
    int tlen = lens[b], slen = lens[8 + b];

    int idx = tlen - 1;
    int y0 = slen - 1;
    int wb;
    uint32_t W0 = 0, W1 = 0, W2 = 0;
    {   // prologue: slab-0 window (one unavoidable stall)
        int yy = y0 - lane; if (yy < 0) yy = 0;
        int qrow = (yy >> 2) * 64, boff = (yy & 3) * 8;
        int t = (idx >> 5) - 1; if (t < 0) t = 0; if (t > 13) t = 13;
        wb = t;
        uint32_t R[12];
        if (lane < 32) {
            RAWLD(R, wb, qrow);
            asm volatile("s_waitcnt vmcnt(0)" ::: "memory");
            __builtin_amdgcn_sched_barrier(0);
            PACKW(W0, W1, W2, R, boff);
        }
    }
    while (y0 >= 0) {
        int w0 = (idx >> 5) - 1; if (w0 < 0) w0 = 0; if (w0 > 14) w0 = 14;
        int s = w0 - wb; if (s < 0) s = 0; if (s > 1) s = 1;
        uint32_t lo = s ? W1 : W0;
        uint32_t hi = s ? W2 : W1;
        int base = (wb + s) << 5;
        // ---- issue next slab's RAW loads (latency hides under the chain) --
        uint32_t N[12];
        int idxm = idx - 32; if (idxm < 0) idxm = 0;
        int wbn = (idxm >> 5) - 1; if (wbn < 0) wbn = 0; if (wbn > 13) wbn = 13;
        int yn = y0 - 32 - lane; if (yn < 0) yn = 0;
        int qn = (yn >> 2) * 64, bn = (yn & 3) * 8;
        if (lane < 32) RAWLD(N, wbn, qn);
        __builtin_amdgcn_sched_barrier(0);
        // ---- 32-step chain ----
        int nsteps = (y0 + 1 < 32) ? y0 + 1 : 32;
        int cap = 0;
#pragma unroll
        for (int j = 0; j < 32; ++j) {
            if (lane == j) cap = idx;
            uint32_t l = (uint32_t)__builtin_amdgcn_readlane((int)lo, j);
            uint32_t h = (uint32_t)__builtin_amdgcn_readlane((int)hi, j);
            int bp = idx - base;              // 0..63 within slab
            uint32_t word = (bp & 32) ? h : l;
            idx -= (int)((word >> (bp & 31)) & 1u);
        }
        __builtin_amdgcn_sched_barrier(0);
        asm volatile("s_waitcnt vmcnt(0)" ::: "memory");   // N landed
        __builtin_amdgcn_sched_barrier(0);
        PACKW(W0, W1, W2, N, bn);
        wb = wbn;
        if (lane < nsteps) {
            int y = y0 - lane;
            idx_map[b * TYY + y] = cap;
            out[((size_t)(b * TYY + y)) * TXX + cap] = 1.0f;       // scatter
            atomicAdd(&out[O4 + b * TXX + cap], 1.0f);             // duration
        }
        y0 -= 32;
    }
}

// Gather m_p/logs_p onto spec frames via idx_map; fused KL partial sums.
__global__ __launch_bounds__(256) void k_gather(const float* __restrict__ z_p,
                                                const float* __restrict__ m_p,
                                                const float* __restrict__ logs_p,
                                                const float* __restrict__ logs_q,
                                                const int* __restrict__ lens,
                                                const int* __restrict__ idx_map,
                                                float* __restrict__ out,
                                                float* __restrict__ partials) {
    const int S = BB * CC * TYY / 4;
    int base = blockIdx.x * 256 + threadIdx.x;
    float klsum = 0.f;
#pragma unroll
    for (int r = 0; r < 4; ++r) {
        int i = base + r * S;
        int t = i & (TYY - 1);
        int bc = i >> 11;
        int b = bc / CC;
        float ma = 0.f, la = 0.f;
        if (t < lens[8 + b]) {
            int x = idx_map[b * TYY + t];
            size_t off = (size_t)bc * TXX + x;
            ma = m_p[off];
            la = logs_p[off];
            float zv = z_p[i], lq = logs_q[i];
            float dz = zv - ma;
            klsum += la - lq - 0.5f + 0.5f * dz * dz * expf(-2.0f * la);
        }
        out[O1 + i] = ma;
        out[O2 + i] = la;
    }
    for (int o = 32; o > 0; o >>= 1) klsum += __shfl_down(klsum, o);
    __shared__ float red[4];
    if ((threadIdx.x & 63) == 0) red[threadIdx.x >> 6] = klsum;
    __syncthreads();
    if (threadIdx.x == 0) partials[blockIdx.x] = red[0] + red[1] + red[2] + red[3];
}

__global__ void k_final(const float* __restrict__ partials, const int* __restrict__ lens,
                        float* __restrict__ out) {
    float s = 0.f;
    for (int i = threadIdx.x; i < 3072; i += 256) s += partials[i];
    for (int o = 32; o > 0; o >>= 1) s += __shfl_down(s, o);
    __shared__ float red[4];
    if ((threadIdx.x & 63) == 0) red[threadIdx.x >> 6] = s;
    __syncthreads();
    if (threadIdx.x == 0) {
        float tot = 0.f;
        for (int b = 0; b < 8; ++b) tot += (float)lens[8 + b];
        out[O3] = (red[0] + red[1] + red[2] + red[3]) / tot;
    }
}

extern "C" void kernel_launch(void* const* d_in, const int* in_sizes, int n_in,
                              void* d_out, int out_size, void* d_ws, size_t ws_size,
                              hipStream_t stream) {
    const float* z_p    = (const float*)d_in[0];
    const float* m_p    = (const float*)d_in[1];
    const float* logs_p = (const float*)d_in[2];
    const float* logs_q = (const float*)d_in[3];
    const float* tmask  = (const float*)d_in[4];
    const float* smask  = (const float*)d_in[5];
    float* out = (float*)d_out;
    char* ws = (char*)d_ws;

    float*    neg      = (float*)(ws + WS_NEG);
    float*    sarr     = (float*)(ws + WS_S);
    float*    msr      = (float*)(ws + WS_MSR);
    float*    bias     = (float*)(ws + WS_BIAS);
    uint32_t* dirs     = (uint32_t*)(ws + WS_DIRS);
    int*      idx_map  = (int*)(ws + WS_IDX);
    int*      lens     = (int*)(ws + WS_LENS);
    float*    partials = (float*)(ws + WS_PART);

    hipLaunchKernelGGL(k_pre,    dim3(PRE_NPREP + PRE_NBIAS + PRE_NLEN),
                       dim3(256), 0, stream,
                       logs_p, m_p, tmask, smask, sarr, msr, bias, lens);
    hipLaunchKernelGGL(k_gz,     dim3(GZ_NZERO + 2048), dim3(256), 0, stream,
                       z_p, msr, sarr, bias, lens, neg, out);
    hipLaunchKernelGGL(k_fwd,    dim3(8),        dim3(64),  0, stream, neg, lens, dirs);
    hipLaunchKernelGGL(k_bwd,    dim3(8),        dim3(64),  0, stream, lens, dirs, idx_map, out);
    hipLaunchKernelGGL(k_gather, dim3(3072),     dim3(256), 0, stream,
                       z_p, m_p, logs_p, logs_q, lens, idx_map, out, partials);
    hipLaunchKernelGGL(k_final,  dim3(1),        dim3(256), 0, stream, partials, lens, out);
}